// Round 3
// baseline (74.238 us; speedup 1.0000x reference)
//
#include <hip/hip_runtime.h>
#include <hip/hip_bf16.h>
#include <hip/hip_fp16.h>
#include <stdint.h>

typedef __hip_bfloat16 bf16;
typedef __attribute__((ext_vector_type(8))) short short8;   // 8 bf16 (4 VGPRs) MFMA A/B frag
typedef __attribute__((ext_vector_type(4))) float f32x4;    // MFMA C/D frag

#define MFMA16(A,B,C) __builtin_amdgcn_mfma_f32_16x16x32_bf16(A,B,C,0,0,0)

// async global->LDS, 16B per lane. LDS dest = wave-uniform base + lane*16.
static __device__ __forceinline__ void g2lds16(const void* g, void* l) {
  __builtin_amdgcn_global_load_lds(
      (__attribute__((address_space(1))) void*)(g),
      (__attribute__((address_space(3))) void*)(l), 16, 0, 0);
}

// swizzled chunk index within a [rows][64 bf16] LDS tile (chunks = 8 bf16 = 16B)
static __device__ __forceinline__ int swz8(int row, int kc) {
  return row * 8 + (kc ^ (row & 7));
}

// ---------------- fp32 -> bf16 elementwise ----------------
__global__ void k_conv_bf16(const float* __restrict__ in, bf16* __restrict__ out, int n4) {
  int i = blockIdx.x * blockDim.x + threadIdx.x;
  if (i < n4) {
    float4 v = ((const float4*)in)[i];
    bf16* po = out + (size_t)i * 4;
    po[0] = __float2bfloat16(v.x);
    po[1] = __float2bfloat16(v.y);
    po[2] = __float2bfloat16(v.z);
    po[3] = __float2bfloat16(v.w);
  }
}

// ---------------- fp32 -> fp16 elementwise (mask) ----------------
__global__ void k_conv_f16(const float* __restrict__ in, __half* __restrict__ out, int n4) {
  int i = blockIdx.x * blockDim.x + threadIdx.x;
  if (i < n4) {
    float4 v = ((const float4*)in)[i];
    __half2* po = (__half2*)(out + (size_t)i * 4);
    po[0] = __floats2half2_rn(v.x, v.y);
    po[1] = __floats2half2_rn(v.z, v.w);
  }
}

// ---------------- transpose + convert: in [R][Ncol] fp32 -> out [Ncol][R] bf16 ----------------
__global__ void k_convT(const float* __restrict__ in, bf16* __restrict__ out, int R, int Ncol) {
  int idx = blockIdx.x * blockDim.x + threadIdx.x;
  if (idx < R * Ncol) {
    int o = idx / R;
    int i = idx - o * R;
    out[idx] = __float2bfloat16(in[(size_t)i * Ncol + o]);
  }
}

// ---------------- bf16 GEMM: C[M][N] = A[M][K] * BT[N][K]^T ----------------
template<int EPI>
__global__ __launch_bounds__(256, 2)
void k_gemm(const bf16* __restrict__ A, const bf16* __restrict__ BT,
            bf16* __restrict__ Cb, float* __restrict__ Cf,
            const float* __restrict__ bias, int M, int N, int K)
{
  __shared__ __align__(16) bf16 As[128 * 64];
  __shared__ __align__(16) bf16 Bs[128 * 64];
  const int tid = threadIdx.x;
  const int wave = tid >> 6, lane = tid & 63;
  const int lhi = lane >> 4, llo = lane & 15;
  const int wr = wave >> 1, wc = wave & 1;
  const int mBase = blockIdx.x * 128, nBase = blockIdx.y * 128;

  f32x4 acc[4][4] = {};

  for (int kt = 0; kt < K; kt += 64) {
    __syncthreads();
    for (int i = 0; i < 4; ++i) {
      int c = (wave * 4 + i) * 64 + lane;      // chunk 0..1023
      int row = c >> 3;
      int kc = (c & 7) ^ (row & 7);            // pre-swizzled global source chunk
      g2lds16(A  + (size_t)(mBase + row) * K + kt + kc * 8, As + (c & ~63) * 8);
      g2lds16(BT + (size_t)(nBase + row) * K + kt + kc * 8, Bs + (c & ~63) * 8);
    }
    __syncthreads();
    for (int kk = 0; kk < 2; ++kk) {
      const int kc = kk * 4 + lhi;
      short8 a[4], b[4];
      for (int mi = 0; mi < 4; ++mi) {
        int row = wr * 64 + mi * 16 + llo;
        a[mi] = *(const short8*)(As + swz8(row, kc) * 8);
      }
      for (int ni = 0; ni < 4; ++ni) {
        int row = wc * 64 + ni * 16 + llo;
        b[ni] = *(const short8*)(Bs + swz8(row, kc) * 8);
      }
      for (int mi = 0; mi < 4; ++mi)
        for (int ni = 0; ni < 4; ++ni)
          acc[mi][ni] = MFMA16(a[mi], b[ni], acc[mi][ni]);
    }
  }

  for (int mi = 0; mi < 4; ++mi)
    for (int ni = 0; ni < 4; ++ni)
      for (int j = 0; j < 4; ++j) {
        int row = mBase + wr * 64 + mi * 16 + lhi * 4 + j;
        int col = nBase + wc * 64 + ni * 16 + llo;
        float v = acc[mi][ni][j];
        if (EPI == 0) {
          if (col < 768) v = fmaxf(v, 0.f) + 1e-6f;   // relu+eps on q,k only
          Cb[(size_t)row * N + col] = __float2bfloat16(v);
        } else {
          Cf[(size_t)row * N + col] = v + bias[col];
        }
      }
}

// ---------------- V transpose: qkv v-section [b,n][h*64+d] -> vT[bh][d][n] ----------------
__global__ void k_transpose_v(const bf16* __restrict__ qkv, bf16* __restrict__ vT) {
  __shared__ bf16 t[64][66];
  int bh = blockIdx.x, b = bh / 6, h = bh - b * 6;
  int n0 = blockIdx.y * 64;
  int r = threadIdx.x >> 2;                 // 0..63
  int cg = (threadIdx.x & 3) * 16;          // 0,16,32,48
  const bf16* src = qkv + ((size_t)b * 1024 + n0 + r) * 1152 + 768 + h * 64 + cg;
  short8 v0 = *(const short8*)src;
  short8 v1 = *(const short8*)(src + 8);
  for (int j = 0; j < 8; ++j) {
    t[r][cg + j]     = ((const bf16*)&v0)[j];
    t[r][cg + 8 + j] = ((const bf16*)&v1)[j];
  }
  __syncthreads();
  short8 o0, o1;
  for (int j = 0; j < 8; ++j) {
    ((bf16*)&o0)[j] = t[cg + j][r];
    ((bf16*)&o1)[j] = t[cg + 8 + j][r];
  }
  bf16* dst = vT + ((size_t)bh * 64 + r) * 1024 + n0 + cg;
  *(short8*)dst = o0;
  *(short8*)(dst + 8) = o1;
}

// ---------------- fused masked linear attention ----------------
// linear bid: bh = bid%48, qt = bid/48  -> all 16 qt-blocks of a bh share
// bid mod 8 -> same XCD -> K/V stay in that XCD's L2; same-qt blocks are
// bid-adjacent -> mask tile L2 reuse. Mask in fp16 (half the bytes).
__global__ __launch_bounds__(256, 3)
void k_attn(const bf16* __restrict__ qkv,   // [8192][1152]
            const bf16* __restrict__ vT,    // [48][64][1024]
            const __half* __restrict__ mask,// [1024][1024] fp16
            bf16* __restrict__ out)         // [8192][384]
{
  __shared__ __align__(16) bf16 Ks[2][64 * 64];
  __shared__ __align__(16) bf16 Vs[2][64 * 64];
  __shared__ __align__(16) bf16 Ps[4][16 * 64];
  const int bid = blockIdx.x;
  const int bh = bid % 48, qt = bid / 48;
  const int b = bh / 6, h = bh - b * 6;
  const int tid = threadIdx.x, wave = tid >> 6, lane = tid & 63;
  const int lhi = lane >> 4, llo = lane & 15;
  const size_t row0 = (size_t)b * 1024;

  // stage K/V tile mt into buffer buf
  auto stageKV = [&](int mt, int buf) {
    for (int i = 0; i < 2; ++i) {
      int c = (wave * 2 + i) * 64 + lane;
      int row = c >> 3;
      int kc = (c & 7) ^ (row & 7);
      g2lds16(qkv + (row0 + mt * 64 + row) * 1152 + 384 + h * 64 + kc * 8,
              Ks[buf] + (c & ~63) * 8);
      g2lds16(vT + ((size_t)bh * 64 + row) * 1024 + mt * 64 + kc * 8,
              Vs[buf] + (c & ~63) * 8);
    }
  };
  stageKV(0, 0);

  // Q fragments direct global->reg (row = qt*64 + wave*16 + llo)
  short8 aq[2];
  {
    const bf16* qp = qkv + (row0 + qt * 64 + wave * 16 + llo) * 1152 + h * 64 + lhi * 8;
    aq[0] = *(const short8*)(qp);
    aq[1] = *(const short8*)(qp + 32);
  }

  f32x4 accO[4] = {};   // [ni] over d
  float zacc[4] = {};   // [j]  row partials

  const __half* mbase = mask + (size_t)(qt * 64 + wave * 16 + lhi * 4) * 1024;

  __syncthreads();   // KV0 resident

  for (int mt = 0; mt < 16; ++mt) {
    const int cur = mt & 1;
    // prefetch next K/V while computing this tile
    if (mt < 15) stageKV(mt + 1, cur ^ 1);

    // preload mask values (independent of S -> latency hidden under QK^T)
    float mreg[4][4];
    for (int j = 0; j < 4; ++j)
      for (int mi = 0; mi < 4; ++mi)
        mreg[j][mi] = __half2float(mbase[(size_t)j * 1024 + mt * 64 + mi * 16 + llo]);

    // S = Q K^T (wave: 16 q-rows x 64 m)
    f32x4 s[4] = {};
    for (int kk = 0; kk < 2; ++kk) {
      const int kc = kk * 4 + lhi;
      short8 bk[4];
      for (int mi = 0; mi < 4; ++mi)
        bk[mi] = *(const short8*)(Ks[cur] + swz8(mi * 16 + llo, kc) * 8);
      for (int mi = 0; mi < 4; ++mi)
        s[mi] = MFMA16(aq[kk], bk[mi], s[mi]);
    }

    // P = S*mask; accumulate z; write P (bf16, swizzled) to per-wave LDS
    bf16* Pw = (bf16*)Ps[wave];
    for (int j = 0; j < 4; ++j) {
      const int qq = lhi * 4 + j;
      float zp = 0.f;
      for (int mi = 0; mi < 4; ++mi) {
        int m = mi * 16 + llo;
        float p = s[mi][j] * mreg[j][mi];
        zp += p;
        Pw[swz8(qq, m >> 3) * 8 + (m & 7)] = __float2bfloat16(p);
      }
      zacc[j] += zp;
    }

    // accO += P @ V  (A = P [16 x 64m], B = Vs [d][m])
    for (int kk = 0; kk < 2; ++kk) {
      const int kc = kk * 4 + lhi;
      short8 ap = *(const short8*)(Pw + swz8(llo, kc) * 8);
      short8 bv[4];
      for (int ni = 0; ni < 4; ++ni)
        bv[ni] = *(const short8*)(Vs[cur] + swz8(ni * 16 + llo, kc) * 8);
      for (int ni = 0; ni < 4; ++ni)
        accO[ni] = MFMA16(ap, bv[ni], accO[ni]);
    }
    __syncthreads();  // next-tile staging complete; all waves done with buf[cur]
  }

  // z reduce across the 16 col-lanes, scale, store
  for (int j = 0; j < 4; ++j) {
    float z = zacc[j];
    z += __shfl_xor(z, 1);
    z += __shfl_xor(z, 2);
    z += __shfl_xor(z, 4);
    z += __shfl_xor(z, 8);
    float zi = 1.f / (z + 1e-6f);
    int n = qt * 64 + wave * 16 + lhi * 4 + j;
    size_t orow = ((size_t)b * 1024 + n) * 384 + h * 64;
    for (int ni = 0; ni < 4; ++ni)
      out[orow + ni * 16 + llo] = __float2bfloat16(accO[ni][j] * zi);
  }
}

extern "C" void kernel_launch(void* const* d_in, const int* in_sizes, int n_in,
                              void* d_out, int out_size, void* d_ws, size_t ws_size,
                              hipStream_t stream) {
  (void)in_sizes; (void)n_in; (void)out_size; (void)ws_size;
  const float* x    = (const float*)d_in[0];   // [8,1024,384]
  const float* wqkv = (const float*)d_in[1];   // [384,1152]
  const float* wout = (const float*)d_in[2];   // [384,384]
  const float* bout = (const float*)d_in[3];   // [384]
  const float* mask = (const float*)d_in[4];   // [1024,1024]
  float* outp = (float*)d_out;

  char* ws = (char*)d_ws;
  bf16*  xb    = (bf16*)(ws);                        // 8192*384       (6,291,456 B)
  bf16*  wqkvT = (bf16*)(ws + 6291456);              // 1152*384       (884,736 B)
  bf16*  woutT = (bf16*)(ws + 7176192);              // 384*384        (294,912 B)
  bf16*  qkvb  = (bf16*)(ws + 7471104);              // 8192*1152      (18,874,368 B)
  bf16*  vTb   = (bf16*)(ws + 26345472);             // 48*64*1024     (6,291,456 B)
  bf16*  ab    = (bf16*)(ws + 32636928);             // 8192*384       (6,291,456 B)
  __half* maskH = (__half*)(ws + 38928384);          // 1024*1024      (2,097,152 B)

  k_conv_bf16<<<dim3(3072), dim3(256), 0, stream>>>(x, xb, 786432);
  k_conv_f16<<<dim3(1024), dim3(256), 0, stream>>>(mask, maskH, 262144);
  k_convT<<<dim3((442368 + 255) / 256), dim3(256), 0, stream>>>(wqkv, wqkvT, 384, 1152);
  k_convT<<<dim3((147456 + 255) / 256), dim3(256), 0, stream>>>(wout, woutT, 384, 384);

  k_gemm<0><<<dim3(64, 9), dim3(256), 0, stream>>>(xb, wqkvT, qkvb, nullptr, nullptr,
                                                   8192, 1152, 384);
  k_transpose_v<<<dim3(48, 16), dim3(256), 0, stream>>>(qkvb, vTb);
  k_attn<<<dim3(768), dim3(256), 0, stream>>>(qkvb, vTb, maskH, ab);
  k_gemm<1><<<dim3(64, 3), dim3(256), 0, stream>>>(ab, woutT, nullptr, outp, bout,
                                                   8192, 384, 384);
}

// Round 5
// 58.807 us; speedup vs baseline: 1.2624x; 1.2624x over previous
//
#include <hip/hip_runtime.h>
#include <hip/hip_bf16.h>
#include <hip/hip_fp16.h>
#include <stdint.h>

typedef __hip_bfloat16 bf16;
typedef __attribute__((ext_vector_type(8))) short short8;    // 8 bf16 MFMA A/B frag
typedef __attribute__((ext_vector_type(4))) float f32x4;
typedef __attribute__((ext_vector_type(16))) float f32x16;   // 32x32 MFMA C/D
typedef __attribute__((ext_vector_type(4))) int int4v;
typedef __attribute__((ext_vector_type(4))) unsigned short ushort4v;

#define MFMA16(A,B,C) __builtin_amdgcn_mfma_f32_16x16x32_bf16(A,B,C,0,0,0)
#define MFMA32(A,B,C) __builtin_amdgcn_mfma_f32_32x32x16_bf16(A,B,C,0,0,0)

#define FENCE() asm volatile("" ::: "memory")
#define SBAR()  do { FENCE(); __builtin_amdgcn_s_barrier(); FENCE(); } while (0)
#define WAITVN(N) asm volatile("s_waitcnt vmcnt(" #N ")" ::: "memory")

// async global->LDS, 16B per lane. LDS dest = wave-uniform base + lane*16.
static __device__ __forceinline__ void g2lds16(const void* g, void* l) {
  __builtin_amdgcn_global_load_lds(
      (__attribute__((address_space(1))) void*)(g),
      (__attribute__((address_space(3))) void*)(l), 16, 0, 0);
}

// swizzled chunk index within a [rows][64 bf16] LDS tile (chunks = 8 bf16 = 16B)
static __device__ __forceinline__ int swz8(int row, int kc) {
  return row * 8 + (kc ^ (row & 7));
}

static __device__ __forceinline__ unsigned short f2bf_bits(float f) {
  bf16 t = __float2bfloat16(f); unsigned short u; __builtin_memcpy(&u, &t, 2); return u;
}
static __device__ __forceinline__ unsigned short f2h_bits(float f) {
  __half t = __float2half(f); unsigned short u; __builtin_memcpy(&u, &t, 2); return u;
}

// ---------------- merged preprocessing ----------------
// tiled transpose+convert: in [R][C] f32 -> out [C][R] u16 (bf16 or fp16)
template<bool HALFOUT>
static __device__ __forceinline__ void tileT(const float* __restrict__ in,
                                             unsigned short* __restrict__ out,
                                             int R, int C, int tr, int tc, int tid,
                                             float (*tls)[65]) {
  const int rr0 = tid >> 4, c4 = tid & 15;
  #pragma unroll
  for (int rr = 0; rr < 4; ++rr) {
    int r = rr0 + rr * 16;
    float4 v = *(const float4*)(in + (size_t)(tr * 64 + r) * C + tc * 64 + c4 * 4);
    tls[r][c4 * 4 + 0] = v.x; tls[r][c4 * 4 + 1] = v.y;
    tls[r][c4 * 4 + 2] = v.z; tls[r][c4 * 4 + 3] = v.w;
  }
  __syncthreads();
  #pragma unroll
  for (int rr = 0; rr < 4; ++rr) {
    int r2 = rr0 + rr * 16;
    ushort4v o;
    #pragma unroll
    for (int k = 0; k < 4; ++k) {
      float f = tls[c4 * 4 + k][r2];
      o[k] = HALFOUT ? f2h_bits(f) : f2bf_bits(f);
    }
    *(ushort4v*)(out + (size_t)(tc * 64 + r2) * R + tr * 64 + c4 * 4) = o;
  }
}

__global__ __launch_bounds__(256)
void k_prep(const float* __restrict__ x, bf16* __restrict__ xb,
            const float* __restrict__ wqkv, unsigned short* __restrict__ wqkvT,
            const float* __restrict__ wout, unsigned short* __restrict__ woutT,
            const float* __restrict__ mask, unsigned short* __restrict__ maskT) {
  __shared__ float tls[64][65];
  const int bid = blockIdx.x, tid = threadIdx.x;
  if (bid < 768) {                       // x fp32 -> bf16: 786432 float4s, 4 per thread
    #pragma unroll
    for (int j = 0; j < 4; ++j) {
      int i = bid * 1024 + j * 256 + tid;
      float4 v = ((const float4*)x)[i];
      bf16* po = xb + (size_t)i * 4;
      po[0] = __float2bfloat16(v.x); po[1] = __float2bfloat16(v.y);
      po[2] = __float2bfloat16(v.z); po[3] = __float2bfloat16(v.w);
    }
  } else if (bid < 876) {                // wqkv [384][1152] -> [1152][384] bf16
    int tt = bid - 768; tileT<false>(wqkv, wqkvT, 384, 1152, tt / 18, tt % 18, tid, tls);
  } else if (bid < 912) {                // wout [384][384] -> [384][384]T bf16
    int tt = bid - 876; tileT<false>(wout, woutT, 384, 384, tt / 6, tt % 6, tid, tls);
  } else {                               // mask [1024][1024] -> maskT fp16
    int tt = bid - 912; tileT<true>(mask, maskT, 1024, 1024, tt / 16, tt % 16, tid, tls);
  }
}

// ---------------- bf16 GEMM: C[M][N] = A[M][K] * BT[N][K]^T (128x128 tile) ----------------
// EPI 0: qkv epilogue: cols<768 relu+eps -> qkvb; cols>=768 -> transposed vT write.
// EPI 1: +bias, fp32 out.
template<int EPI>
__global__ __launch_bounds__(256, 2)
void k_gemm(const bf16* __restrict__ A, const bf16* __restrict__ BT,
            bf16* __restrict__ Cb, float* __restrict__ Cf,
            const float* __restrict__ bias, bf16* __restrict__ vT,
            int M, int N, int K)
{
  __shared__ __align__(16) bf16 As[128 * 64];
  __shared__ __align__(16) bf16 Bs[128 * 64];
  const int tid = threadIdx.x;
  const int wave = tid >> 6, lane = tid & 63;
  const int lhi = lane >> 4, llo = lane & 15;
  const int wr = wave >> 1, wc = wave & 1;
  const int mBase = blockIdx.x * 128, nBase = blockIdx.y * 128;

  f32x4 acc[4][4] = {};

  for (int kt = 0; kt < K; kt += 64) {
    __syncthreads();
    for (int i = 0; i < 4; ++i) {
      int c = (wave * 4 + i) * 64 + lane;
      int row = c >> 3;
      int kc = (c & 7) ^ (row & 7);
      g2lds16(A  + (size_t)(mBase + row) * K + kt + kc * 8, As + (c & ~63) * 8);
      g2lds16(BT + (size_t)(nBase + row) * K + kt + kc * 8, Bs + (c & ~63) * 8);
    }
    __syncthreads();
    for (int kk = 0; kk < 2; ++kk) {
      const int kc = kk * 4 + lhi;
      short8 a[4], b[4];
      for (int mi = 0; mi < 4; ++mi)
        a[mi] = *(const short8*)(As + swz8(wr * 64 + mi * 16 + llo, kc) * 8);
      for (int ni = 0; ni < 4; ++ni)
        b[ni] = *(const short8*)(Bs + swz8(wc * 64 + ni * 16 + llo, kc) * 8);
      for (int mi = 0; mi < 4; ++mi)
        for (int ni = 0; ni < 4; ++ni)
          acc[mi][ni] = MFMA16(a[mi], b[ni], acc[mi][ni]);
    }
  }

  for (int mi = 0; mi < 4; ++mi)
    for (int ni = 0; ni < 4; ++ni) {
      const int colbase = nBase + wc * 64 + ni * 16;
      if (EPI == 1) {
        for (int j = 0; j < 4; ++j) {
          int row = mBase + wr * 64 + mi * 16 + lhi * 4 + j;
          int col = colbase + llo;
          Cf[(size_t)row * N + col] = acc[mi][ni][j] + bias[col];
        }
      } else if (colbase < 768) {
        for (int j = 0; j < 4; ++j) {
          int row = mBase + wr * 64 + mi * 16 + lhi * 4 + j;
          int col = colbase + llo;
          float v = fmaxf(acc[mi][ni][j], 0.f) + 1e-6f;   // relu+eps on q,k
          Cb[(size_t)row * N + col] = __float2bfloat16(v);
        }
      } else {                                             // v-section -> vT[bh][d][n]
        int col = colbase + llo;
        int dall = col - 768, hh = dall >> 6, dd = dall & 63;
        int rowg = mBase + wr * 64 + mi * 16 + lhi * 4;
        int bb = rowg >> 10, nloc = rowg & 1023;
        ushort4v pk;
        for (int j = 0; j < 4; ++j) pk[j] = f2bf_bits(acc[mi][ni][j]);
        *(ushort4v*)((unsigned short*)vT + (((size_t)bb * 6 + hh) * 64 + dd) * 1024 + nloc) = pk;
      }
    }
}

// ---------------- fused masked linear attention (32x32 MFMA, swapped QK^T) ----------------
// grid 768: bh = bid%48, qt = bid/48 (QBLK=64). 4 waves: wq=wave&1 (q-half),
// wm=wave>>1 (m-half of each 64-m tile). K/V double-buffered, counted vmcnt,
// raw barriers (prefetch stays in flight). P stays in registers via cvt_pk +
// lane-32 exchange. Cross-wave (wm) O/z reduction in LDS at the end.
__global__ __launch_bounds__(256, 3)
void k_attn(const bf16* __restrict__ qkv,     // [8192][1152] (q,k sections)
            const bf16* __restrict__ vT,      // [48][64][1024]
            const __half* __restrict__ maskT, // [1024 m][1024 q] fp16
            bf16* __restrict__ out)           // [8192][384]
{
  __shared__ __align__(16) bf16 Ks[2][64 * 64];
  __shared__ __align__(16) bf16 Vs[2][64 * 64];
  __shared__ float Ored[2][32][65];
  __shared__ float zred[2][2][32];

  const int bid = blockIdx.x;
  const int bh = bid % 48, qt = bid / 48;
  const int b = bh / 6, h = bh - b * 6;
  const int tid = threadIdx.x, wave = tid >> 6, lane = tid & 63;
  const int lq = lane & 31, lh = lane >> 5;
  const int wq = wave & 1, wm = wave >> 1;
  const size_t row0 = (size_t)b * 1024;
  const int qglob = qt * 64 + wq * 32 + lq;

  auto stageKV = [&](int mt, int buf) {
    #pragma unroll
    for (int i = 0; i < 2; ++i) {
      int c = (wave * 2 + i) * 64 + lane;
      int row = c >> 3;
      int kc = (c & 7) ^ (row & 7);
      g2lds16(qkv + (row0 + mt * 64 + row) * 1152 + 384 + h * 64 + kc * 8,
              Ks[buf] + (c & ~63) * 8);
      g2lds16(vT + ((size_t)bh * 64 + row) * 1024 + mt * 64 + kc * 8,
              Vs[buf] + (c & ~63) * 8);
    }
  };

  // Q fragments (B-operand): lane holds Q[qglob][ks*16 + lh*8 + e]
  short8 bq[4];
  {
    const bf16* qp = qkv + (row0 + qglob) * 1152 + h * 64 + lh * 8;
    #pragma unroll
    for (int ks = 0; ks < 4; ++ks) bq[ks] = *(const short8*)(qp + ks * 16);
  }
  stageKV(0, 0);

  f32x16 accO[2] = {};   // [db] : O[q 32][d 32] quadrants
  float zl = 0.f;

  #pragma unroll 1
  for (int mt = 0; mt < 16; ++mt) {
    const int cur = mt & 1;
    const bf16* Kc = Ks[cur];
    const bf16* Vc = Vs[cur];

    // mask tile values (fp16, keep unconverted so the wait lands after barrier)
    __half mv[16];
    {
      const int mrow0 = mt * 64 + wm * 32 + 4 * lh;
      #pragma unroll
      for (int g = 0; g < 4; ++g)
        #pragma unroll
        for (int j = 0; j < 4; ++j)
          mv[g * 4 + j] = maskT[(size_t)(mrow0 + 8 * g + j) * 1024 + qglob];
    }
    if (mt < 15) {
      stageKV(mt + 1, cur ^ 1);
      WAITVN(20);            // drain stage(mt): 16 mask + 4 stage(mt+1) stay in flight
    } else {
      WAITVN(16);
    }
    SBAR();                  // buf[cur] fully populated across waves

    // S^T[32m][32q] = K . Q^T over d=64 (4 k-steps)
    f32x16 st = {};
    #pragma unroll
    for (int ks = 0; ks < 4; ++ks) {
      int row = wm * 32 + lq;
      int cc = (ks * 2 + lh) ^ (row & 7);
      short8 af = *(const short8*)(Kc + (row * 8 + cc) * 8);
      st = MFMA32(af, bq[ks], st);
    }

    // P = S*mask (f32), z partial, pack to bf16 PA-frags in registers
    float p[16];
    {
      float zp = 0.f;
      #pragma unroll
      for (int r = 0; r < 16; ++r) {
        p[r] = st[r] * __half2float(mv[r]);
        zp += p[r];
      }
      zl += zp;
    }
    int u[4][2];
    #pragma unroll
    for (int g = 0; g < 4; ++g)
      #pragma unroll
      for (int c = 0; c < 2; ++c)
        asm("v_cvt_pk_bf16_f32 %0, %1, %2"
            : "=v"(u[g][c]) : "v"(p[4 * g + 2 * c]), "v"(p[4 * g + 2 * c + 1]));

    short8 pa[2];
    #pragma unroll
    for (int ks = 0; ks < 2; ++ks) {
      int A0 = u[2 * ks][0], A0b = u[2 * ks][1];
      int A1 = u[2 * ks + 1][0], A1b = u[2 * ks + 1][1];
      int x0 = __shfl_xor(A0, 32), x1 = __shfl_xor(A0b, 32);
      int y0 = __shfl_xor(A1, 32), y1 = __shfl_xor(A1b, 32);
      int4v iv;
      iv.x = lh ? y0 : A0;    // e 0,1
      iv.y = lh ? y1 : A0b;   // e 2,3
      iv.z = lh ? A1 : x0;    // e 4,5
      iv.w = lh ? A1b : x1;   // e 6,7
      pa[ks] = *(short8*)&iv;
    }

    // O[q][d] += P . V^T  (b-frag rows = V^T[d][m])
    #pragma unroll
    for (int db = 0; db < 2; ++db)
      #pragma unroll
      for (int ks = 0; ks < 2; ++ks) {
        int row = db * 32 + lq;
        int cc = (wm * 4 + ks * 2 + lh) ^ (row & 7);
        short8 vb = *(const short8*)(Vc + (row * 8 + cc) * 8);
        accO[db] = MFMA32(pa[ks], vb, accO[db]);
      }

    SBAR();                  // all waves done reading buf[cur]
  }

  // cross-wave (wm) reduction of O and z, scale, store
  zl += __shfl_xor(zl, 32);
  zred[wq][wm][lq] = zl;
  if (wm == 1) {
    #pragma unroll
    for (int db = 0; db < 2; ++db)
      #pragma unroll
      for (int r = 0; r < 16; ++r) {
        int q = (r & 3) + 8 * (r >> 2) + 4 * lh;
        Ored[wq][q][db * 32 + lq] = accO[db][r];
      }
  }
  __syncthreads();
  if (wm == 0) {
    #pragma unroll
    for (int r = 0; r < 16; ++r) {
      int q = (r & 3) + 8 * (r >> 2) + 4 * lh;
      float zt = zred[wq][0][q] + zred[wq][1][q];
      float zi = 1.f / (zt + 1e-6f);
      int n = qt * 64 + wq * 32 + q;
      size_t orow = (row0 + n) * 384 + h * 64;
      #pragma unroll
      for (int db = 0; db < 2; ++db) {
        float val = (accO[db][r] + Ored[wq][q][db * 32 + lq]) * zi;
        out[orow + db * 32 + lq] = __float2bfloat16(val);
      }
    }
  }
}

// ---------------- out-projection GEMM: 64x64 tile, 32x32 MFMA ----------------
__global__ __launch_bounds__(256, 3)
void k_gemm_out(const bf16* __restrict__ A, const bf16* __restrict__ BT,
                float* __restrict__ Cf, const float* __restrict__ bias)
{
  __shared__ __align__(16) bf16 As[64 * 64];
  __shared__ __align__(16) bf16 Bs[64 * 64];
  const int tid = threadIdx.x;
  const int wave = tid >> 6, lane = tid & 63;
  const int lq = lane & 31, lh = lane >> 5;
  const int wr = wave >> 1, wc = wave & 1;
  const int mBase = blockIdx.x * 64, nBase = blockIdx.y * 64;
  const int N = 384, K = 384;

  f32x16 acc = {};
  for (int kt = 0; kt < K; kt += 64) {
    __syncthreads();
    #pragma unroll
    for (int i = 0; i < 2; ++i) {
      int c = (wave * 2 + i) * 64 + lane;
      int row = c >> 3;
      int kc = (c & 7) ^ (row & 7);
      g2lds16(A  + (size_t)(mBase + row) * K + kt + kc * 8, As + (c & ~63) * 8);
      g2lds16(BT + (size_t)(nBase + row) * K + kt + kc * 8, Bs + (c & ~63) * 8);
    }
    __syncthreads();
    #pragma unroll
    for (int ks = 0; ks < 4; ++ks) {
      int ra = wr * 32 + lq, rb = wc * 32 + lq;
      short8 a = *(const short8*)(As + (ra * 8 + ((ks * 2 + lh) ^ (ra & 7))) * 8);
      short8 b = *(const short8*)(Bs + (rb * 8 + ((ks * 2 + lh) ^ (rb & 7))) * 8);
      acc = MFMA32(a, b, acc);
    }
  }
  #pragma unroll
  for (int r = 0; r < 16; ++r) {
    int row = mBase + wr * 32 + (r & 3) + 8 * (r >> 2) + 4 * lh;
    int col = nBase + wc * 32 + lq;
    Cf[(size_t)row * N + col] = acc[r] + bias[col];
  }
}

extern "C" void kernel_launch(void* const* d_in, const int* in_sizes, int n_in,
                              void* d_out, int out_size, void* d_ws, size_t ws_size,
                              hipStream_t stream) {
  (void)in_sizes; (void)n_in; (void)out_size; (void)ws_size;
  const float* x    = (const float*)d_in[0];   // [8,1024,384]
  const float* wqkv = (const float*)d_in[1];   // [384,1152]
  const float* wout = (const float*)d_in[2];   // [384,384]
  const float* bout = (const float*)d_in[3];   // [384]
  const float* mask = (const float*)d_in[4];   // [1024,1024]
  float* outp = (float*)d_out;

  char* ws = (char*)d_ws;
  bf16*  xb    = (bf16*)(ws);                  // 8192*384
  bf16*  wqkvT = (bf16*)(ws + 6291456);        // 1152*384
  bf16*  woutT = (bf16*)(ws + 7176192);        // 384*384
  bf16*  qkvb  = (bf16*)(ws + 7471104);        // 8192*1152 (q,k only)
  bf16*  vTb   = (bf16*)(ws + 26345472);       // 48*64*1024
  bf16*  ab    = (bf16*)(ws + 32636928);       // 8192*384
  __half* maskT = (__half*)(ws + 38928384);    // 1024*1024 fp16 (transposed)

  k_prep<<<dim3(1168), dim3(256), 0, stream>>>(
      x, xb, wqkv, (unsigned short*)wqkvT, wout, (unsigned short*)woutT,
      mask, (unsigned short*)maskT);

  k_gemm<0><<<dim3(64, 9), dim3(256), 0, stream>>>(xb, wqkvT, qkvb, nullptr, nullptr,
                                                   vTb, 8192, 1152, 384);
  k_attn<<<dim3(768), dim3(256), 0, stream>>>(qkvb, vTb, maskT, ab);
  k_gemm_out<<<dim3(128, 6), dim3(256), 0, stream>>>(ab, woutT, outp, bout);
}